// Round 4
// 366.222 us; speedup vs baseline: 1.0616x; 1.0616x over previous
//
#include <hip/hip_runtime.h>

// BilinearLayer: out = sigmoid( (E @ Bs_r) @ E^T ) per (b,r)
// B=8 R=8 N=1024 F=256.  All compute in f16 MFMA (16x16x32), fp32 accum.
//
// ws layout (in _Float16 elements):
//   wsE   [64][32][1024][8]  : E  fp16, fragment layout [br][f/8][n][8]   (32 MB)
//   wsBsT [8][32][256][8]    : Bs^T fp16, [r][f/8][g][8]                  (1 MB)
//   wse   [64][32][1024][8]  : e  fp16, [br][g/8][n][8]                   (32 MB)
// total 68,157,440 bytes of d_ws.
//
// R4 == R3 resubmit (R1-R3 all died to "container failed twice"; R3 already
// removed global_load_lds, the only plausible kernel-side killer, and is a
// near-clone of the round-0 kernel that ran at 389 us -> infra failure).
// Change set vs round 0:
//  - swapped MFMA operands -> transposed D fragment -> vectorized epilogues
//    (gemm2: float4 stores; gemm1: f16x4 stores)
//  - XCD-aware blockIdx swizzle (per-XCD br locality in private L2)
//  - register-staged loads issued before the first barrier (latency overlap)

typedef float    f32x4 __attribute__((ext_vector_type(4)));
typedef _Float16 f16x8 __attribute__((ext_vector_type(8)));
typedef _Float16 f16x4 __attribute__((ext_vector_type(4)));

#define WS_E_OFF   0
#define WS_BST_OFF 16777216
#define WS_e_OFF   17301504

// ---------------- kernel 0: convert / layout transform ----------------
__global__ __launch_bounds__(256) void bl_convert(
    const float* __restrict__ E, const float* __restrict__ Bs,
    _Float16* __restrict__ wsE, _Float16* __restrict__ wsBsT) {
  int bid = blockIdx.x, tid = threadIdx.x;
  if (bid < 8192) {
    // E: [br][n][f] fp32  ->  [br][fc][n][8] fp16
    int cid = (bid << 8) + tid;          // 2,097,152 chunks
    int br  = cid >> 15;
    int rem = cid & 32767;
    int fc  = rem >> 10;
    int n   = rem & 1023;                // n fast -> coalesced 16B writes
    const float* src = E + ((size_t)br << 18) + n * 256 + (fc << 3);
    f32x4 v0 = *(const f32x4*)src;
    f32x4 v1 = *(const f32x4*)(src + 4);
    f16x8 h;
    h[0] = (_Float16)v0[0]; h[1] = (_Float16)v0[1];
    h[2] = (_Float16)v0[2]; h[3] = (_Float16)v0[3];
    h[4] = (_Float16)v1[0]; h[5] = (_Float16)v1[1];
    h[6] = (_Float16)v1[2]; h[7] = (_Float16)v1[3];
    *(f16x8*)(wsE + ((size_t)br << 18) + (fc << 13) + (n << 3)) = h;
  } else {
    // Bs: [r][f][g] fp32 -> BsT fp16 [r][fc][g][8]  (transpose)
    int cid = ((bid - 8192) << 8) + tid; // 65,536 chunks
    int r   = cid >> 13;
    int rem = cid & 8191;
    int fc  = rem >> 8;
    int g   = rem & 255;                 // g fast -> coalesced reads per j
    const float* src = Bs + (r << 16) + (fc << 3) * 256 + g;
    f16x8 h;
#pragma unroll
    for (int j = 0; j < 8; ++j) h[j] = (_Float16)src[j * 256];
    *(f16x8*)(wsBsT + (r << 16) + (fc << 11) + (g << 3)) = h;
  }
}

// ---------------- kernel 1: e = E @ Bs_r  (fp16 in, fp16 out) ----------------
// grid: 64 br * (8 n-tiles * 2 g-tiles) = 1024 blocks, 256 thr (4 waves)
// block tile 128x128, BK=64; wave tile 64x64 = 4x4 mfma_f32_16x16x32_f16
// operands SWAPPED: D rows = g, D cols = n  -> per-lane 4 consecutive g.
__global__ __launch_bounds__(256) void bl_gemm1(
    const _Float16* __restrict__ wsE, const _Float16* __restrict__ wsBsT,
    _Float16* __restrict__ wse) {
  __shared__ _Float16 sA[8192];   // [kcl(8)][row(128)][8]
  __shared__ _Float16 sB[8192];
  int b0  = blockIdx.x;
  int bid = ((b0 & 7) << 7) + (b0 >> 3);   // XCD swizzle (1024 = 8*128)
  int br = bid >> 4;
  int t  = bid & 15;
  int n0 = (t >> 1) << 7;
  int g0 = (t & 1) << 7;
  int r  = br & 7;
  int tid  = threadIdx.x;
  int lane = tid & 63, wave = tid >> 6;
  int wm = wave >> 1, wn = wave & 1;
  int quad = lane >> 4, l16 = lane & 15;

  const _Float16* aG = wsE   + ((size_t)br << 18) + (n0 << 3); // + kc*8192 + nl*8
  const _Float16* bG = wsBsT + (r << 16) + (g0 << 3);          // + kc*2048 + gl*8

  f32x4 acc[4][4] = {};

  for (int kk = 0; kk < 4; ++kk) {
    // register-staged loads (round-0 proven path)
    f16x8 va[4], vb[4];
#pragma unroll
    for (int i = 0; i < 4; ++i) {
      int c = (i << 8) + tid;
      int kcl = c >> 7, nl = c & 127;
      va[i] = *(const f16x8*)(aG + (((kk << 3) + kcl) << 13) + (nl << 3));
    }
#pragma unroll
    for (int i = 0; i < 4; ++i) {
      int c = (i << 8) + tid;
      int kcl = c >> 7, gl = c & 127;
      vb[i] = *(const f16x8*)(bG + (((kk << 3) + kcl) << 11) + (gl << 3));
    }
    __syncthreads();               // prior iter's ds_reads done
#pragma unroll
    for (int i = 0; i < 4; ++i) {
      int c = (i << 8) + tid;
      *(f16x8*)&sA[c << 3] = va[i];
      *(f16x8*)&sB[c << 3] = vb[i];
    }
    __syncthreads();
#pragma unroll
    for (int ks = 0; ks < 2; ++ks) {
      int kc = (ks << 2) + quad;
      f16x8 af[4], bf[4];
#pragma unroll
      for (int rt = 0; rt < 4; ++rt)
        af[rt] = *(const f16x8*)&sA[((kc << 7) + (wm << 6) + (rt << 4) + l16) << 3];
#pragma unroll
      for (int ct = 0; ct < 4; ++ct)
        bf[ct] = *(const f16x8*)&sB[((kc << 7) + (wn << 6) + (ct << 4) + l16) << 3];
#pragma unroll
      for (int rt = 0; rt < 4; ++rt)
#pragma unroll
        for (int ct = 0; ct < 4; ++ct)
          acc[rt][ct] = __builtin_amdgcn_mfma_f32_16x16x32_f16(bf[ct], af[rt], acc[rt][ct], 0, 0, 0);
    }
  }
  // epilogue: D[g][n] fragment: col=l16 -> n, row=quad*4+i -> g.
  // e layout [gc][n][8]: per-lane 4 consecutive g = 8B contiguous store.
  _Float16* eB = wse + ((size_t)br << 18);
#pragma unroll
  for (int rt = 0; rt < 4; ++rt) {
    int n = n0 + (wm << 6) + (rt << 4) + l16;
#pragma unroll
    for (int ct = 0; ct < 4; ++ct) {
      int g  = g0 + (wn << 6) + (ct << 4) + (quad << 2);
      int gc = g >> 3, gj = g & 7;         // gj in {0,4}
      f16x4 h;
#pragma unroll
      for (int i = 0; i < 4; ++i) h[i] = (_Float16)acc[rt][ct][i];
      *(f16x4*)(eB + (gc << 13) + (n << 3) + gj) = h;
    }
  }
}

// ---------------- kernel 2: out = sigmoid(e @ E^T) ----------------
// grid: 64 br * 8 n-tiles * 8 m-tiles = 4096 blocks
// operands SWAPPED: D rows = m, D cols = n -> per-lane 4 consecutive m
// -> float4 output stores.
__global__ __launch_bounds__(256) void bl_gemm2(
    const _Float16* __restrict__ wse, const _Float16* __restrict__ wsE,
    float* __restrict__ out) {
  __shared__ _Float16 sA[8192];
  __shared__ _Float16 sB[8192];
  int b0  = blockIdx.x;
  int bid = ((b0 & 7) << 9) + (b0 >> 3);   // XCD swizzle (4096 = 8*512)
  int br = bid >> 6;
  int t  = bid & 63;
  int n0 = (t >> 3) << 7;
  int m0 = (t & 7) << 7;
  int tid  = threadIdx.x;
  int lane = tid & 63, wave = tid >> 6;
  int wm = wave >> 1, wn = wave & 1;
  int quad = lane >> 4, l16 = lane & 15;

  const _Float16* aG = wse + ((size_t)br << 18) + (n0 << 3);
  const _Float16* bG = wsE + ((size_t)br << 18) + (m0 << 3);

  f32x4 acc[4][4] = {};

  for (int kk = 0; kk < 4; ++kk) {
    f16x8 va[4], vb[4];
#pragma unroll
    for (int i = 0; i < 4; ++i) {
      int c = (i << 8) + tid;
      int kcl = c >> 7, nl = c & 127;
      va[i] = *(const f16x8*)(aG + (((kk << 3) + kcl) << 13) + (nl << 3));
    }
#pragma unroll
    for (int i = 0; i < 4; ++i) {
      int c = (i << 8) + tid;
      int kcl = c >> 7, ml = c & 127;
      vb[i] = *(const f16x8*)(bG + (((kk << 3) + kcl) << 13) + (ml << 3));
    }
    __syncthreads();
#pragma unroll
    for (int i = 0; i < 4; ++i) {
      int c = (i << 8) + tid;
      *(f16x8*)&sA[c << 3] = va[i];
      *(f16x8*)&sB[c << 3] = vb[i];
    }
    __syncthreads();
#pragma unroll
    for (int ks = 0; ks < 2; ++ks) {
      int kc = (ks << 2) + quad;
      f16x8 af[4], bf[4];
#pragma unroll
      for (int rt = 0; rt < 4; ++rt)
        af[rt] = *(const f16x8*)&sA[((kc << 7) + (wm << 6) + (rt << 4) + l16) << 3];
#pragma unroll
      for (int ct = 0; ct < 4; ++ct)
        bf[ct] = *(const f16x8*)&sB[((kc << 7) + (wn << 6) + (ct << 4) + l16) << 3];
#pragma unroll
      for (int rt = 0; rt < 4; ++rt)
#pragma unroll
        for (int ct = 0; ct < 4; ++ct)
          acc[rt][ct] = __builtin_amdgcn_mfma_f32_16x16x32_f16(bf[ct], af[rt], acc[rt][ct], 0, 0, 0);
    }
  }
  // epilogue: D[m][n]: col=l16 -> n, row=quad*4+i -> m. float4 store along m.
  float* oB = out + ((size_t)br << 20);
#pragma unroll
  for (int rt = 0; rt < 4; ++rt) {
    int n = n0 + (wm << 6) + (rt << 4) + l16;
#pragma unroll
    for (int ct = 0; ct < 4; ++ct) {
      int m = m0 + (wn << 6) + (ct << 4) + (quad << 2);
      f32x4 v;
#pragma unroll
      for (int i = 0; i < 4; ++i) {
        float x = acc[rt][ct][i];
        v[i] = __builtin_amdgcn_rcpf(1.0f + __expf(-x));
      }
      *(f32x4*)(oB + ((size_t)n << 10) + m) = v;
    }
  }
}

extern "C" void kernel_launch(void* const* d_in, const int* in_sizes, int n_in,
                              void* d_out, int out_size, void* d_ws, size_t ws_size,
                              hipStream_t stream) {
  const float* E  = (const float*)d_in[0];   // [8,8,1024,256]
  const float* Bs = (const float*)d_in[1];   // [8,256,256]
  _Float16* wsE   = (_Float16*)d_ws + WS_E_OFF;
  _Float16* wsBsT = (_Float16*)d_ws + WS_BST_OFF;
  _Float16* wse   = (_Float16*)d_ws + WS_e_OFF;
  float* out = (float*)d_out;

  bl_convert<<<8448, 256, 0, stream>>>(E, Bs, wsE, wsBsT);
  bl_gemm1<<<1024, 256, 0, stream>>>(wsE, wsBsT, wse);
  bl_gemm2<<<4096, 256, 0, stream>>>(wse, wsE, out);
}